// Round 1
// baseline (555.553 us; speedup 1.0000x reference)
//
#include <hip/hip_runtime.h>
#include <hip/hip_bf16.h>
#include <math.h>

#define T_TOK 4096
#define D_DIM 1024
#define E_EXP 8
#define F_DIM 4096
#define BM 128
#define BN 128
#define BK 32
#define LDK 40          // padded LDS row stride (bf16 elems): 20 dwords -> conflict-free b128
#define MAX_TILES 40    // sum_e ceil(cnt_e/128) <= 4096/128 + 7 = 39

typedef __attribute__((ext_vector_type(8))) short short8;
typedef __attribute__((ext_vector_type(4))) float float4v;

__device__ __forceinline__ short f2b(float f) {
    union { float f; unsigned u; } v; v.f = f;
    unsigned r = v.u + 0x7fffu + ((v.u >> 16) & 1u);   // RNE to bf16
    return (short)(r >> 16);
}

// ---------------- router: fp32 logits + argmax (exact routing) ----------------
__global__ void router_kernel(const float* __restrict__ x, const float* __restrict__ gw,
                              int* __restrict__ eid, int* __restrict__ rnk,
                              int* __restrict__ counts) {
    int lane = threadIdx.x & 63;
    int wave = threadIdx.x >> 6;
    int t = blockIdx.x * 4 + wave;
    const float* xr = x + (size_t)t * D_DIM;
    float p[E_EXP];
#pragma unroll
    for (int e = 0; e < E_EXP; ++e) p[e] = 0.f;
#pragma unroll
    for (int i = 0; i < D_DIM / 64; ++i) {
        float v = xr[lane + 64 * i];
#pragma unroll
        for (int e = 0; e < E_EXP; ++e)
            p[e] = fmaf(v, gw[e * D_DIM + lane + 64 * i], p[e]);
    }
#pragma unroll
    for (int off = 32; off > 0; off >>= 1) {
#pragma unroll
        for (int e = 0; e < E_EXP; ++e) p[e] += __shfl_down(p[e], off, 64);
    }
    if (lane == 0) {
        int best = 0; float bv = p[0];
#pragma unroll
        for (int e = 1; e < E_EXP; ++e) if (p[e] > bv) { bv = p[e]; best = e; }
        eid[t] = best;
        rnk[t] = atomicAdd(&counts[best], 1);
    }
}

// ---------------- prefix + tile map (trivial, E=8) ----------------
__global__ void prefix_kernel(const int* __restrict__ counts, int* __restrict__ offsets,
                              int* __restrict__ tmap) {
    int off = 0;
    offsets[0] = 0;
    int nt = 0;
    for (int e = 0; e < E_EXP; ++e) {
        int c = counts[e];
        for (int m0 = 0; m0 < c; m0 += BM) {
            tmap[nt * 3 + 0] = e;
            tmap[nt * 3 + 1] = off + m0;
            tmap[nt * 3 + 2] = (c - m0 < BM) ? (c - m0) : BM;
            ++nt;
        }
        off += c;
        offsets[e + 1] = off;
    }
    for (; nt < MAX_TILES; ++nt) tmap[nt * 3 + 2] = 0;
}

__global__ void scatter_kernel(const int* __restrict__ eid, const int* __restrict__ rnk,
                               const int* __restrict__ offsets, int* __restrict__ sorted) {
    int t = blockIdx.x * 256 + threadIdx.x;
    sorted[offsets[eid[t]] + rnk[t]] = t;
}

// ---------------- grouped GEMM1: h = gelu(x_gathered @ w1[e]), bf16 out ----------------
__global__ __launch_bounds__(256) void gemm1_kernel(const float* __restrict__ x,
                                                    const float* __restrict__ w1,
                                                    const int* __restrict__ sorted,
                                                    const int* __restrict__ tmap,
                                                    short* __restrict__ hbuf) {
    __shared__ short As[BM * LDK];
    __shared__ short Bs[BN * LDK];
    __shared__ int srow[BM];
    int mt = blockIdx.y;
    int m_count = tmap[mt * 3 + 2];
    if (m_count == 0) return;
    int e = tmap[mt * 3 + 0];
    int row0 = tmap[mt * 3 + 1];
    int n0 = blockIdx.x * BN;
    int tid = threadIdx.x;
    if (tid < BM) srow[tid] = sorted[row0 + (tid < m_count ? tid : m_count - 1)];
    __syncthreads();

    int lane = tid & 63, wave = tid >> 6;
    int wm = (wave & 1) * 64, wn = (wave >> 1) * 64;
    float4v acc[4][4];
#pragma unroll
    for (int i = 0; i < 4; ++i)
#pragma unroll
        for (int j = 0; j < 4; ++j) acc[i][j] = (float4v)(0.f);

    int ar = tid >> 1;               // A row 0..127
    int ac = (tid & 1) * 16;         // A k-offset 0/16
    int bn = tid & 127;              // B col 0..127
    int bq = (tid >> 7) * 16;        // B k-offset 0/16
    const float* abase = x + (size_t)srow[ar] * D_DIM + ac;
    const float* bbase = w1 + (size_t)e * D_DIM * F_DIM + (size_t)bq * F_DIM + (n0 + bn);

    for (int k0 = 0; k0 < D_DIM; k0 += BK) {
        {   // A stage: fp32 -> bf16, row-major [m][k]
            const float* ap = abase + k0;
            float4v f0 = *(const float4v*)(ap);
            float4v f1 = *(const float4v*)(ap + 4);
            float4v f2 = *(const float4v*)(ap + 8);
            float4v f3 = *(const float4v*)(ap + 12);
            short8 s0, s1;
#pragma unroll
            for (int c = 0; c < 4; ++c) {
                s0[c] = f2b(f0[c]); s0[4 + c] = f2b(f1[c]);
                s1[c] = f2b(f2[c]); s1[4 + c] = f2b(f3[c]);
            }
            *(short8*)(&As[ar * LDK + ac]) = s0;
            *(short8*)(&As[ar * LDK + ac + 8]) = s1;
        }
        {   // B stage: column loads (coalesced across lanes), LDS as [n][k]
            const float* bp = bbase + (size_t)k0 * F_DIM;
            float v[16];
#pragma unroll
            for (int j = 0; j < 16; ++j) v[j] = bp[(size_t)j * F_DIM];
            short8 s0, s1;
#pragma unroll
            for (int j = 0; j < 8; ++j) { s0[j] = f2b(v[j]); s1[j] = f2b(v[8 + j]); }
            *(short8*)(&Bs[bn * LDK + bq]) = s0;
            *(short8*)(&Bs[bn * LDK + bq + 8]) = s1;
        }
        __syncthreads();
        short8 af[4], bf[4];
#pragma unroll
        for (int i = 0; i < 4; ++i)
            af[i] = *(const short8*)(&As[(wm + i * 16 + (lane & 15)) * LDK + (lane >> 4) * 8]);
#pragma unroll
        for (int j = 0; j < 4; ++j)
            bf[j] = *(const short8*)(&Bs[(wn + j * 16 + (lane & 15)) * LDK + (lane >> 4) * 8]);
#pragma unroll
        for (int i = 0; i < 4; ++i)
#pragma unroll
            for (int j = 0; j < 4; ++j)
                acc[i][j] = __builtin_amdgcn_mfma_f32_16x16x32_bf16(af[i], bf[j], acc[i][j], 0, 0, 0);
        __syncthreads();
    }
    // epilogue: exact gelu, store bf16 h in expert-sorted order
    int rbase = (lane >> 4) * 4;
    int cbase = lane & 15;
#pragma unroll
    for (int i = 0; i < 4; ++i) {
#pragma unroll
        for (int r = 0; r < 4; ++r) {
            int row = wm + i * 16 + rbase + r;
            if (row < m_count) {
                short* hp = hbuf + (size_t)(row0 + row) * F_DIM + n0 + wn + cbase;
#pragma unroll
                for (int j = 0; j < 4; ++j) {
                    float s = acc[i][j][r];
                    float g = 0.5f * s * (1.f + erff(s * 0.70710678118f));
                    hp[j * 16] = f2b(g);
                }
            }
        }
    }
}

// ---------------- grouped GEMM2: out = h @ w2[e], scatter fp32 ----------------
__global__ __launch_bounds__(256) void gemm2_kernel(const short* __restrict__ hbuf,
                                                    const float* __restrict__ w2,
                                                    const int* __restrict__ sorted,
                                                    const int* __restrict__ tmap,
                                                    float* __restrict__ out) {
    __shared__ short As[BM * LDK];
    __shared__ short Bs[BN * LDK];
    __shared__ int srow[BM];
    int mt = blockIdx.y;
    int m_count = tmap[mt * 3 + 2];
    if (m_count == 0) return;
    int e = tmap[mt * 3 + 0];
    int row0 = tmap[mt * 3 + 1];
    int n0 = blockIdx.x * BN;
    int tid = threadIdx.x;
    if (tid < BM) srow[tid] = sorted[row0 + (tid < m_count ? tid : m_count - 1)];
    __syncthreads();

    int lane = tid & 63, wave = tid >> 6;
    int wm = (wave & 1) * 64, wn = (wave >> 1) * 64;
    float4v acc[4][4];
#pragma unroll
    for (int i = 0; i < 4; ++i)
#pragma unroll
        for (int j = 0; j < 4; ++j) acc[i][j] = (float4v)(0.f);

    int ar = tid >> 1;
    int ac = (tid & 1) * 16;
    int bn = tid & 127;
    int bq = (tid >> 7) * 16;
    int arc = ar < m_count ? ar : m_count - 1;    // clamp: don't read past valid h rows
    const short* abase = hbuf + (size_t)(row0 + arc) * F_DIM + ac;
    const float* bbase = w2 + (size_t)e * F_DIM * D_DIM + (size_t)bq * D_DIM + (n0 + bn);

    for (int k0 = 0; k0 < F_DIM; k0 += BK) {
        {   // A stage: already bf16, straight 16B copies
            const short* ap = abase + k0;
            *(short8*)(&As[ar * LDK + ac]) = *(const short8*)(ap);
            *(short8*)(&As[ar * LDK + ac + 8]) = *(const short8*)(ap + 8);
        }
        {   // B stage
            const float* bp = bbase + (size_t)k0 * D_DIM;
            float v[16];
#pragma unroll
            for (int j = 0; j < 16; ++j) v[j] = bp[(size_t)j * D_DIM];
            short8 s0, s1;
#pragma unroll
            for (int j = 0; j < 8; ++j) { s0[j] = f2b(v[j]); s1[j] = f2b(v[8 + j]); }
            *(short8*)(&Bs[bn * LDK + bq]) = s0;
            *(short8*)(&Bs[bn * LDK + bq + 8]) = s1;
        }
        __syncthreads();
        short8 af[4], bf[4];
#pragma unroll
        for (int i = 0; i < 4; ++i)
            af[i] = *(const short8*)(&As[(wm + i * 16 + (lane & 15)) * LDK + (lane >> 4) * 8]);
#pragma unroll
        for (int j = 0; j < 4; ++j)
            bf[j] = *(const short8*)(&Bs[(wn + j * 16 + (lane & 15)) * LDK + (lane >> 4) * 8]);
#pragma unroll
        for (int i = 0; i < 4; ++i)
#pragma unroll
            for (int j = 0; j < 4; ++j)
                acc[i][j] = __builtin_amdgcn_mfma_f32_16x16x32_bf16(af[i], bf[j], acc[i][j], 0, 0, 0);
        __syncthreads();
    }
    // epilogue: scatter fp32 rows back to original token positions
    int rbase = (lane >> 4) * 4;
    int cbase = lane & 15;
#pragma unroll
    for (int i = 0; i < 4; ++i) {
#pragma unroll
        for (int r = 0; r < 4; ++r) {
            int row = wm + i * 16 + rbase + r;
            if (row < m_count) {
                float* op = out + (size_t)srow[row] * D_DIM + n0 + wn + cbase;
#pragma unroll
                for (int j = 0; j < 4; ++j) op[j * 16] = acc[i][j][r];
            }
        }
    }
}

extern "C" void kernel_launch(void* const* d_in, const int* in_sizes, int n_in,
                              void* d_out, int out_size, void* d_ws, size_t ws_size,
                              hipStream_t stream) {
    const float* x  = (const float*)d_in[0];
    const float* gw = (const float*)d_in[1];
    const float* w1 = (const float*)d_in[2];
    const float* w2 = (const float*)d_in[3];
    float* out = (float*)d_out;
    char* ws = (char*)d_ws;

    int* counts  = (int*)(ws);            // 8 ints
    int* offsets = (int*)(ws + 64);       // 9 ints
    int* tmap    = (int*)(ws + 128);      // 40*3 ints
    int* eid     = (int*)(ws + 1024);     // 4096 ints
    int* rnk     = (int*)(ws + 17408);    // 4096 ints
    int* sorted  = (int*)(ws + 33792);    // 4096 ints
    short* hbuf  = (short*)(ws + 51200);  // 4096*4096 bf16 = 33.55 MB

    hipMemsetAsync(counts, 0, 32, stream);
    router_kernel<<<T_TOK / 4, 256, 0, stream>>>(x, gw, eid, rnk, counts);
    prefix_kernel<<<1, 1, 0, stream>>>(counts, offsets, tmap);
    scatter_kernel<<<T_TOK / 256, 256, 0, stream>>>(eid, rnk, offsets, sorted);
    gemm1_kernel<<<dim3(F_DIM / BN, MAX_TILES), 256, 0, stream>>>(x, w1, sorted, tmap, hbuf);
    gemm2_kernel<<<dim3(D_DIM / BN, MAX_TILES), 256, 0, stream>>>(hbuf, w2, sorted, tmap, out);
}